// Round 5
// baseline (438.857 us; speedup 1.0000x reference)
//
#include <hip/hip_runtime.h>
#include <hip/hip_bf16.h>

// x:[1024,3,32,32] -> conv1(3->64)+relu -> conv2(64->128)+relu -> meanpool
// -> fc(128->256)+b -> *mask -> sage1(256->256)+relu -> sage2(256->128)
// Output [32,32,128] fp32.
//
// Workspace layout (<6MB):
//  [0,512K)      pooled [1024][128] f32 (atomic accumulation, zeroed in prep)
//  [2M,3M)       z1 [1024][256]
//  [3M,4M)       z2 [1024][256]
//  [4096K,+256K) l1T  [256][256] = s1lw^T
//  [4352K,+256K) w1pT [256][256] = (s1rw - s1lw/31)^T
//  [4608K,+128K) l2T  [256][128] = s2lw^T
//  [4736K,+128K) w2pT [256][128] = (s2rw - s2lw/31)^T
//  [4864K,+128K) fwT  [128][256] = fc_w^T
//  [4992K,+144K) w2c  [9][4][2][128][8] bf16 conv2 w: [tap][ks][hi][oc][j],
//                ic = ks*16 + hi*8 + j  (B-frag order for 32x32x16 MFMA)
//  [5136K,+4K)   w1b  [64][32] bf16 conv1 w+bias (k=27 slot = bias)

typedef __attribute__((ext_vector_type(8))) short bfrag;
typedef __attribute__((ext_vector_type(4))) float f32x4;
typedef __attribute__((ext_vector_type(16))) float f32x16;

static __device__ __forceinline__ unsigned short f2bf(float f) {
    union { float f; unsigned u; } v; v.f = f;
    unsigned r = v.u + 0x7fff + ((v.u >> 16) & 1);   // RNE (finite)
    return (unsigned short)(r >> 16);
}

// pack two f32 -> two bf16 (RNE) in one instr
static __device__ __forceinline__ unsigned cvtpk(float lo, float hi) {
    unsigned r;
    asm("v_cvt_pk_bf16_f32 %0, %1, %2" : "=v"(r) : "v"(lo), "v"(hi));
    return r;
}

__global__ __launch_bounds__(256) void prep_kernel(
    const float* __restrict__ s1lw, const float* __restrict__ s1rw,
    const float* __restrict__ s2lw, const float* __restrict__ s2rw,
    const float* __restrict__ c2w, const float* __restrict__ c1w,
    const float* __restrict__ c1b, const float* __restrict__ fcw,
    float* __restrict__ l1T, float* __restrict__ w1pT,
    float* __restrict__ l2T, float* __restrict__ w2pT,
    float* __restrict__ fwT,
    short* __restrict__ w2c, short* __restrict__ w1b,
    float* __restrict__ pooled) {
    int i = blockIdx.x * 256 + threadIdx.x;     // grid 288 -> [0, 73728)
    const float inv31 = 1.f / 31.f;
    if (i < 65536) {
        int d = i >> 8, o = i & 255;
        float lw = s1lw[o * 256 + d];
        l1T[i]  = lw;
        w1pT[i] = s1rw[o * 256 + d] - lw * inv31;
        pooled[i] = 0.f;                        // zero for atomic pooling
        pooled[i + 65536] = 0.f;
    }
    if (i < 32768) {
        int d = i >> 7, o = i & 127;
        float lw = s2lw[o * 256 + d];
        l2T[i]  = lw;
        w2pT[i] = s2rw[o * 256 + d] - lw * inv31;
        int c = i >> 8, o2 = i & 255;
        fwT[i] = fcw[o2 * 128 + c];
    }
    if (i < 73728) {        // w2c[tap][ks][hi][oc][j] = c2w[oc][ic][tap]
        int tap = i >> 13, r = i & 8191;
        int ks = r >> 11, hi = (r >> 10) & 1, oc = (r >> 3) & 127, j = i & 7;
        int ic = ks * 16 + hi * 8 + j;
        w2c[i] = (short)f2bf(c2w[(oc * 64 + ic) * 9 + tap]);
    }
    if (i < 2048) {                             // w1b[oc][k], k=27 -> bias
        int oc = i >> 5, k = i & 31;
        float v = (k < 27) ? c1w[oc * 27 + k] : (k == 27 ? c1b[oc] : 0.f);
        w1b[i] = (short)f2bf(v);
    }
}

// Fused conv1+conv2+pool. R5: grid (2 halves of 16 rows, 1024 imgs).
//  R1-R4 all converged to ~165us / 44% MfmaUtil: with a 128-AGPR acc,
//  operand traffic (1/R + 1/OT = 0.75 b128 per MFMA) saturates whichever
//  pipe carries it (LDS 85 B/cyc or L1 64 B/cyc) at exactly the MFMA rate.
//  Fix: 256-AGPR acc (wave = 4 rows x 128 oc; reads/MFMA = 0.5) -> LDS 768
//  + L1 533 cyc/step, both < MFMA 1024. Costs: 1 wave/SIMD (4-wave block,
//  1 block/CU, <=512 regs/wave). Consequences exploited:
//   - ZERO barriers in the K-loop (per-wave vmcnt dep-tracking; only sync is
//     the phase A -> B __syncthreads). Waves free-run their own pipelines.
//   - c1t ichi-blocked [ichi 8][row 18][col 34][iclo 8]: af ds_read_b128 is
//     contiguous 512B per half-wave -> conflict-free without pad-72.
//   - B frags from global, double-buffered in regs; L1 catches 4-wave reuse.
__global__ __launch_bounds__(256, 1) void fused_conv_kernel(
    const float* __restrict__ x, const short* __restrict__ w1b,
    const short* __restrict__ w2c, const float* __restrict__ b2,
    float* __restrict__ pooled) {
    const int half = blockIdx.x, img = blockIdx.y;
    __shared__ short xt[3 * 20 * 34];        // 4080 B: img rows half*16-2..+17
    __shared__ short c1t[8 * 18 * 34 * 8];   // 78336 B [ichi][s][col][iclo]
    __shared__ float wsum[4][128];
    const int t = threadIdx.x;
    const int w = t >> 6, lane = t & 63;
    const int ln15 = lane & 15, q8 = (lane >> 4) * 8, q = lane >> 4;
    const int ln31 = lane & 31, hi = lane >> 5;

    // stage xt (zero-padded). xt[c][xr][col]: img row = half*16-2+xr, x = col-1
    const float* xi = x + img * 3072;
    for (int idx = t; idx < 2040; idx += 256) {
        int c = idx / 680, rem = idx % 680, xr = rem / 34, col = rem % 34;
        int y = half * 16 - 2 + xr, xx = col - 1;
        float v = 0.f;
        if ((unsigned)y < 32u && (unsigned)xx < 32u) v = xi[c * 1024 + y * 32 + xx];
        xt[idx] = (short)f2bf(v);
    }
    // zero col halo of c1t (cols 0 and 33, every ichi/row)
    for (int i = t; i < 288; i += 256) {
        int ichi = i / 36, rem = i % 36, s = rem >> 1, side = rem & 1;
        *(uint4*)&c1t[ichi * 4896 + s * 272 + side * 33 * 8] = uint4{0u, 0u, 0u, 0u};
    }
    bfrag b1f[4];
#pragma unroll
    for (int ot = 0; ot < 4; ++ot)
        b1f[ot] = *(const bfrag*)(w1b + (ot * 16 + ln15) * 32 + q8);

    // hoisted per-lane conv1 tap decomposition (invariant over pos tiles)
    int xOff[8]; int kMask[8]; int kOvr[8];
#pragma unroll
    for (int j = 0; j < 8; ++j) {
        int k = q8 + j;
        int c = (k * 57) >> 9;               // k/9 for k<36
        int rem = k - 9 * c;
        int dy = (rem * 11) >> 5;            // rem/3 for rem<9
        int dx = rem - 3 * dy;
        int cc = c < 3 ? c : 2;              // clamp for safe read
        xOff[j] = cc * 680 + dy * 34 + dx;
        kMask[j] = (c < 3) ? 0xFFFF : 0;
        kOvr[j]  = (c < 3) ? 0 : (k == 27 ? 0x3F80 : 0);
    }
    __syncthreads();

    // ---- phase A: conv1 -> c1t. 36 pos-tiles of 16 (18 rows x 32 cols,
    //      storage rows 0..17 = img rows half*16-1 .. +16; out-of-image rows
    //      masked to zero = conv2 zero padding). wave w -> tiles 9w..9w+8.
    //      weights = A-operand, x patch = B-operand. ----
#pragma unroll 1
    for (int pt = 0; pt < 9; ++pt) {
        const int tile = w * 9 + pt;
        const int s = tile >> 1, cb = (tile & 1) << 4;
        const int baseA = s * 34 + cb + ln15;    // xt row = s + dy (see xOff)
        bfrag a1f;
#pragma unroll
        for (int j = 0; j < 8; ++j)
            a1f[j] = (short)((xt[xOff[j] + baseA] & kMask[j]) | kOvr[j]);
        f32x4 acc1[4];
#pragma unroll
        for (int ot = 0; ot < 4; ++ot) {
#pragma unroll
            for (int rg = 0; rg < 4; ++rg) acc1[ot][rg] = 0.f;
            acc1[ot] = __builtin_amdgcn_mfma_f32_16x16x32_bf16(
                b1f[ot], a1f, acc1[ot], 0, 0, 0);
        }
        // D: row = oc (ot*16 + q*4 + rg), col = pos (cb + ln15).
        // write [ichi = 2ot + (q>>1)][s][col+1][iclo = (q&1)*4 + rg]
        const int imgrow = half * 16 - 1 + s;
        const bool valid = (unsigned)imgrow < 32u;   // tile-uniform
        const int wbase = s * 272 + (cb + ln15 + 1) * 8 + (q & 1) * 4;
#pragma unroll
        for (int ot = 0; ot < 4; ++ot) {
            uint2 pk = {0u, 0u};
            if (valid) {
                pk.x = cvtpk(fmaxf(acc1[ot][0], 0.f), fmaxf(acc1[ot][1], 0.f));
                pk.y = cvtpk(fmaxf(acc1[ot][2], 0.f), fmaxf(acc1[ot][3], 0.f));
            }
            *(uint2*)&c1t[(2 * ot + (q >> 1)) * 4896 + wbase] = pk;
        }
    }
    __syncthreads();   // c1t ready; no further barriers until epilogue

    // ---- phase B: conv2, 32x32x16 MFMA. wave = 4 rows x 32 cols x 128 oc ----
    float b2v[4];
#pragma unroll
    for (int ot = 0; ot < 4; ++ot) b2v[ot] = b2[ot * 32 + ln31];

    f32x16 acc[4][4];
#pragma unroll
    for (int rp = 0; rp < 4; ++rp)
#pragma unroll
        for (int ot = 0; ot < 4; ++ot)
#pragma unroll
            for (int rg = 0; rg < 16; ++rg) acc[rp][ot][rg] = 0.f;

    // af addr (shorts): (4*kh + 2*kk + hi)*4896 + (w*4 + rp + dy)*272
    //                   + (ln31 + dx)*8
    const int afBase = hi * 4896 + (w * 4) * 272 + ln31 * 8;
    const short* bBase = w2c + hi * 1024 + ln31 * 8;

    bfrag bX[8], bY[8];
    auto loadB = [&](bfrag* bf, int st) {     // 8 x global_load_dwordx4
        const short* p = bBase + (st >> 1) * 8192 + (st & 1) * 4096;
#pragma unroll
        for (int kk = 0; kk < 2; ++kk)
#pragma unroll
            for (int ot = 0; ot < 4; ++ot)
                bf[kk * 4 + ot] = *(const bfrag*)(p + kk * 2048 + ot * 256);
    };
    auto body = [&](int st, const bfrag* bc, bfrag* bn) {
        if (st + 1 < 18) loadB(bn, st + 1);   // completes under the 32 MFMAs
        const int tap = st >> 1, kh = st & 1;
        const int dy = (tap * 11) >> 5, dx = tap - 3 * dy;
        const int a0 = afBase + kh * 19584 + dy * 272 + dx * 8;
        bfrag af[8];
#pragma unroll
        for (int rp = 0; rp < 4; ++rp)
#pragma unroll
            for (int kk = 0; kk < 2; ++kk)
                af[rp * 2 + kk] = *(const bfrag*)&c1t[a0 + rp * 272 + kk * 9792];
        __builtin_amdgcn_s_setprio(1);
#pragma unroll
        for (int kk = 0; kk < 2; ++kk)
#pragma unroll
            for (int rp = 0; rp < 4; ++rp)
#pragma unroll
                for (int ot = 0; ot < 4; ++ot)
                    acc[rp][ot] = __builtin_amdgcn_mfma_f32_32x32x16_bf16(
                        af[rp * 2 + kk], bc[kk * 4 + ot], acc[rp][ot], 0, 0, 0);
        __builtin_amdgcn_s_setprio(0);
    };

    loadB(bX, 0);
#pragma unroll 1
    for (int st = 0; st < 18; st += 2) {      // X/Y shadow-reg pipeline
        body(st, bX, bY);
        body(st + 1, bY, bX);
    }

    // bias + relu + pool. 32x32 C/D: col(lane&31)=oc, rows (=positions)
    // spread over regs & half-wave -> per-lane covers 16 of 32 pos; xor 32.
#pragma unroll
    for (int ot = 0; ot < 4; ++ot) {
        float s = 0.f;
#pragma unroll
        for (int rp = 0; rp < 4; ++rp)
#pragma unroll
            for (int rg = 0; rg < 16; ++rg)
                s += fmaxf(acc[rp][ot][rg] + b2v[ot], 0.f);
        s += __shfl_xor(s, 32, 64);
        if (lane < 32) wsum[w][ot * 32 + ln31] = s;
    }
    __syncthreads();
    if (t < 128) {
        atomicAdd(&pooled[(size_t)img * 128 + t],
                  wsum[0][t] + wsum[1][t] + wsum[2][t] + wsum[3][t]);
    }
}

// fc: grid 256 (4 images per block) -- amortizes fwT L2 refetch 4x.
__global__ __launch_bounds__(256) void fc_kernel(
    const float* __restrict__ pooled, const float* __restrict__ fwT,
    const float* __restrict__ fb, const float* __restrict__ mask,
    float* __restrict__ z1) {
    const int g = blockIdx.x;
    __shared__ float m[4][128];
    const int t = threadIdx.x;
    if (t < 128) {
#pragma unroll
        for (int i = 0; i < 4; ++i)
            m[i][t] = pooled[(size_t)(g * 4 + i) * 128 + t] * (1.f / 1024.f);
    }
    __syncthreads();
    float a0 = fb[t], a1 = a0, a2 = a0, a3 = a0;
#pragma unroll 4
    for (int c = 0; c < 128; ++c) {
        float wv = fwT[c * 256 + t];                 // coalesced
        a0 = fmaf(m[0][c], wv, a0);
        a1 = fmaf(m[1][c], wv, a1);
        a2 = fmaf(m[2][c], wv, a2);
        a3 = fmaf(m[3][c], wv, a3);
    }
    z1[(g * 4 + 0) * 256 + t] = a0 * mask[g * 4 + 0];
    z1[(g * 4 + 1) * 256 + t] = a1 * mask[g * 4 + 1];
    z1[(g * 4 + 2) * 256 + t] = a2 * mask[g * 4 + 2];
    z1[(g * 4 + 3) * 256 + t] = a3 * mask[g * 4 + 3];
}

// sage1+relu: grid 256 = (bb, chunk of 4 nodes); thread t = output o.
__global__ __launch_bounds__(256) void sage1_kernel(
    const float* __restrict__ z1, const float* __restrict__ l1T,
    const float* __restrict__ lb, const float* __restrict__ w1pT,
    float* __restrict__ z2) {
    const int bb = blockIdx.x >> 3, chunk = blockIdx.x & 7;
    __shared__ float h[32 * 256];
    __shared__ float sl[256];
    const int t = threadIdx.x;
    const float* zb = z1 + bb * 8192;
    for (int idx = t; idx < 8192; idx += 256) h[idx] = zb[idx];
    __syncthreads();
    float s = 0.f;
#pragma unroll
    for (int n = 0; n < 32; ++n) s += h[n * 256 + t];
    sl[t] = s * (1.f / 31.f);
    __syncthreads();
    float c = lb[t];
#pragma unroll 4
    for (int d = 0; d < 256; ++d) c = fmaf(sl[d], l1T[d * 256 + t], c);
    float acc[4];
#pragma unroll
    for (int i = 0; i < 4; ++i) acc[i] = c;
    for (int d0 = 0; d0 < 256; d0 += 4) {
        float wv0 = w1pT[(d0 + 0) * 256 + t];
        float wv1 = w1pT[(d0 + 1) * 256 + t];
        float wv2 = w1pT[(d0 + 2) * 256 + t];
        float wv3 = w1pT[(d0 + 3) * 256 + t];
#pragma unroll
        for (int i = 0; i < 4; ++i) {
            f32x4 hv = *(const f32x4*)&h[(chunk * 4 + i) * 256 + d0];  // LDS broadcast
            acc[i] = fmaf(hv[0], wv0, acc[i]);
            acc[i] = fmaf(hv[1], wv1, acc[i]);
            acc[i] = fmaf(hv[2], wv2, acc[i]);
            acc[i] = fmaf(hv[3], wv3, acc[i]);
        }
    }
    for (int i = 0; i < 4; ++i)
        z2[(bb * 32 + chunk * 4 + i) * 256 + t] = fmaxf(acc[i], 0.f);
}

// sage2: grid 256 = (bb, chunk of 4 nodes); o = t&127, half = t>>7 (2 nodes each).
__global__ __launch_bounds__(256) void sage2_kernel(
    const float* __restrict__ z2, const float* __restrict__ l2T,
    const float* __restrict__ lb, const float* __restrict__ w2pT,
    float* __restrict__ out) {
    const int bb = blockIdx.x >> 3, chunk = blockIdx.x & 7;
    __shared__ float h[32 * 256];
    __shared__ float sl[256];
    const int t = threadIdx.x;
    const float* zb = z2 + bb * 8192;
    for (int idx = t; idx < 8192; idx += 256) h[idx] = zb[idx];
    __syncthreads();
    float s = 0.f;
#pragma unroll
    for (int n = 0; n < 32; ++n) s += h[n * 256 + t];
    sl[t] = s * (1.f / 31.f);
    __syncthreads();
    const int o = t & 127, half = t >> 7;
    float c = lb[o];
#pragma unroll 4
    for (int d = 0; d < 256; ++d) c = fmaf(sl[d], l2T[d * 128 + o], c);
    float acc[2];
    acc[0] = c; acc[1] = c;
    const int n0 = chunk * 4 + half * 2;
    for (int d0 = 0; d0 < 256; d0 += 4) {
        float wv0 = w2pT[(d0 + 0) * 128 + o];
        float wv1 = w2pT[(d0 + 1) * 128 + o];
        float wv2 = w2pT[(d0 + 2) * 128 + o];
        float wv3 = w2pT[(d0 + 3) * 128 + o];
#pragma unroll
        for (int ii = 0; ii < 2; ++ii) {
            f32x4 hv = *(const f32x4*)&h[(n0 + ii) * 256 + d0];
            acc[ii] = fmaf(hv[0], wv0, acc[ii]);
            acc[ii] = fmaf(hv[1], wv1, acc[ii]);
            acc[ii] = fmaf(hv[2], wv2, acc[ii]);
            acc[ii] = fmaf(hv[3], wv3, acc[ii]);
        }
    }
    for (int ii = 0; ii < 2; ++ii)
        out[(size_t)(bb * 32 + n0 + ii) * 128 + o] = acc[ii];
}

extern "C" void kernel_launch(void* const* d_in, const int* in_sizes, int n_in,
                              void* d_out, int out_size, void* d_ws, size_t ws_size,
                              hipStream_t stream) {
    const float* x    = (const float*)d_in[0];
    const float* mask = (const float*)d_in[1];
    const float* c1w  = (const float*)d_in[2];
    const float* c1b  = (const float*)d_in[3];
    const float* c2w  = (const float*)d_in[4];
    const float* c2b  = (const float*)d_in[5];
    const float* fcw  = (const float*)d_in[6];
    const float* fcb  = (const float*)d_in[7];
    const float* s1lw = (const float*)d_in[8];
    const float* s1lb = (const float*)d_in[9];
    const float* s1rw = (const float*)d_in[10];
    const float* s2lw = (const float*)d_in[11];
    const float* s2lb = (const float*)d_in[12];
    const float* s2rw = (const float*)d_in[13];
    float* out = (float*)d_out;

    char* ws = (char*)d_ws;
    float* pooled  = (float*)(ws);
    float* z1      = (float*)(ws + 2048u * 1024);
    float* z2      = (float*)(ws + 3072u * 1024);
    float* l1T     = (float*)(ws + 4096u * 1024);
    float* w1pT    = (float*)(ws + 4352u * 1024);
    float* l2T     = (float*)(ws + 4608u * 1024);
    float* w2pT    = (float*)(ws + 4736u * 1024);
    float* fwT     = (float*)(ws + 4864u * 1024);
    short* w2c     = (short*)(ws + 4992u * 1024);
    short* w1b     = (short*)(ws + 5136u * 1024);

    prep_kernel<<<dim3(288), 256, 0, stream>>>(s1lw, s1rw, s2lw, s2rw, c2w, c1w, c1b,
                                               fcw, l1T, w1pT, l2T, w2pT, fwT, w2c, w1b,
                                               pooled);
    fused_conv_kernel<<<dim3(2, 1024), 256, 0, stream>>>(x, w1b, w2c, c2b, pooled);
    fc_kernel<<<dim3(256), 256, 0, stream>>>(pooled, fwT, fcb, mask, z1);
    sage1_kernel<<<dim3(256), 256, 0, stream>>>(z1, l1T, s1lb, w1pT, z2);
    sage2_kernel<<<dim3(256), 256, 0, stream>>>(z2, l2T, s2lb, w2pT, out);
}

// Round 6
// 293.817 us; speedup vs baseline: 1.4936x; 1.4936x over previous
//
#include <hip/hip_runtime.h>
#include <hip/hip_bf16.h>

// x:[1024,3,32,32] -> conv1(3->64)+relu -> conv2(64->128)+relu -> meanpool
// -> fc(128->256)+b -> *mask -> sage1(256->256)+relu -> sage2(256->128)
// Output [32,32,128] fp32.
//
// Workspace layout (<6MB):
//  [0,2M)        pooled4 [1024][4][128] f32 (band partials, pre-divide)
//  [2M,3M)       z1 [1024][256]
//  [3M,4M)       z2 [1024][256]
//  [4096K,+256K) l1T  [256][256] = s1lw^T
//  [4352K,+256K) w1pT [256][256] = (s1rw - s1lw/31)^T
//  [4608K,+128K) l2T  [256][128] = s2lw^T
//  [4736K,+128K) w2pT [256][128] = (s2rw - s2lw/31)^T
//  [4864K,+128K) fwT  [128][256] = fc_w^T
//  [4992K,+144K) w2c  [9][4][2][128][8] bf16 conv2 w: [tap][ks][hi][oc][j],
//                ic = ks*16 + hi*8 + j  (B-frag order for 32x32x16 MFMA)
//  [5136K,+4K)   w1b  [64][32] bf16 conv1 w+bias (k=27 slot = bias)

typedef __attribute__((ext_vector_type(8))) short bfrag;
typedef __attribute__((ext_vector_type(4))) float f32x4;
typedef __attribute__((ext_vector_type(16))) float f32x16;

static __device__ __forceinline__ unsigned short f2bf(float f) {
    union { float f; unsigned u; } v; v.f = f;
    unsigned r = v.u + 0x7fff + ((v.u >> 16) & 1);   // RNE (finite)
    return (unsigned short)(r >> 16);
}

// pack two f32 -> two bf16 (RNE) in one instr
static __device__ __forceinline__ unsigned cvtpk(float lo, float hi) {
    unsigned r;
    asm("v_cvt_pk_bf16_f32 %0, %1, %2" : "=v"(r) : "v"(lo), "v"(hi));
    return r;
}

// async global->LDS, 16B per lane (linear dest = wave-uniform base + lane*16)
static __device__ __forceinline__ void gl_lds16(const short* g, short* l) {
    __builtin_amdgcn_global_load_lds(
        (const __attribute__((address_space(1))) unsigned int*)g,
        (__attribute__((address_space(3))) unsigned int*)l, 16, 0, 0);
}

__global__ __launch_bounds__(256) void prep_kernel(
    const float* __restrict__ s1lw, const float* __restrict__ s1rw,
    const float* __restrict__ s2lw, const float* __restrict__ s2rw,
    const float* __restrict__ c2w, const float* __restrict__ c1w,
    const float* __restrict__ c1b, const float* __restrict__ fcw,
    float* __restrict__ l1T, float* __restrict__ w1pT,
    float* __restrict__ l2T, float* __restrict__ w2pT,
    float* __restrict__ fwT,
    short* __restrict__ w2c, short* __restrict__ w1b) {
    int i = blockIdx.x * 256 + threadIdx.x;     // grid 288 -> [0, 73728)
    const float inv31 = 1.f / 31.f;
    if (i < 65536) {
        int d = i >> 8, o = i & 255;
        float lw = s1lw[o * 256 + d];
        l1T[i]  = lw;
        w1pT[i] = s1rw[o * 256 + d] - lw * inv31;
    }
    if (i < 32768) {
        int d = i >> 7, o = i & 127;
        float lw = s2lw[o * 256 + d];
        l2T[i]  = lw;
        w2pT[i] = s2rw[o * 256 + d] - lw * inv31;
        int c = i >> 8, o2 = i & 255;
        fwT[i] = fcw[o2 * 128 + c];
    }
    if (i < 73728) {        // w2c[tap][ks][hi][oc][j] = c2w[oc][ic][tap]
        int tap = i >> 13, r = i & 8191;
        int ks = r >> 11, hi = (r >> 10) & 1, oc = (r >> 3) & 127, j = i & 7;
        int ic = ks * 16 + hi * 8 + j;
        w2c[i] = (short)f2bf(c2w[(oc * 64 + ic) * 9 + tap]);
    }
    if (i < 2048) {                             // w1b[oc][k], k=27 -> bias
        int oc = i >> 5, k = i & 31;
        float v = (k < 27) ? c1w[oc * 27 + k] : (k == 27 ? c1b[oc] : 0.f);
        w1b[i] = (short)f2bf(v);
    }
}

// Fused conv1+conv2+pool: grid (4 bands of 8 rows, 1024 imgs). R6:
//  R5 post-mortem: 256-AGPR acc spilled (VGPR capped 256, 13MB scratch).
//  Revert to R4 geometry. New model fitting R1-R5: R3/R4 were LDS-BW-bound
//  (LDS 1340 vs MFMA 1033 cyc/step/CU, measured 1356 -> full overlap, LDS is
//  the max); R1 put all B on L1 (1024 = MFMA); R2 L1 1500 > MFMA 775. Every
//  config had the whole B stream on ONE pipe sized >= MFMA. Fix: SPLIT B --
//  kk=0 half staged to LDS (4KB/step, triple buffer), kk=1 half streamed from
//  global into double-buffered regs. LDS 862, L1 512, MFMA 1033 -> MFMA is
//  the unique max. Counted vmcnt(4) at step end (stage done; B-prefetch stays
//  in flight across the barrier -- T4).
__global__ __launch_bounds__(256, 2) void fused_conv_kernel(
    const float* __restrict__ x, const short* __restrict__ w1b,
    const short* __restrict__ w2c, const float* __restrict__ b2,
    float* __restrict__ pooled4) {
    const int band = blockIdx.x, img = blockIdx.y;
    __shared__ short xt[3 * 12 * 34];     // 2448 B: input rows band*8-2..band*8+9
    __shared__ short c1t[10 * 34 * 72];   // 48960 B [row][col pad34][ic pad72]
    __shared__ short bufB[3][2048];       // 12288 B: 3 x 4KB kk=0 half-chunks
    __shared__ float wsum[4][128];
    const int t = threadIdx.x;
    const int w = t >> 6, lane = t & 63;
    const int ln15 = lane & 15, q8 = (lane >> 4) * 8;
    const int ln31 = lane & 31, hi = lane >> 5;

    // stage xt (zero-padded), zero c1t pad cols 0/33
    const float* xi = x + img * 3072;
    for (int idx = t; idx < 1224; idx += 256) {
        int c = idx / 408, rem = idx % 408, r = rem / 34, col = rem % 34;
        int y = band * 8 - 2 + r, xx = col - 1;
        float v = 0.f;
        if ((unsigned)y < 32u && (unsigned)xx < 32u) v = xi[c * 1024 + y * 32 + xx];
        xt[idx] = (short)f2bf(v);
    }
    {
        f32x4 z = {0.f, 0.f, 0.f, 0.f};
        for (int i = t; i < 180; i += 256) {          // 10r x 2c x 9 f32x4
            int r = i / 18, rem = i % 18, side = rem / 9, q = rem % 9;
            *(f32x4*)(c1t + (r * 34 + side * 33) * 72 + q * 8) = z;
        }
    }
    bfrag b1f[4];
#pragma unroll
    for (int ot = 0; ot < 4; ++ot)
        b1f[ot] = *(const bfrag*)(w1b + (ot * 16 + ln15) * 32 + q8);

    // hoisted per-lane conv1 tap decomposition (invariant over pos tiles)
    int xOff[8]; int kMask[8]; int kOvr[8];
#pragma unroll
    for (int j = 0; j < 8; ++j) {
        int k = q8 + j;
        int c = (k * 57) >> 9;               // k/9 for k<36
        int rem = k - 9 * c;
        int dy = (rem * 11) >> 5;            // rem/3 for rem<9
        int dx = rem - 3 * dy;
        int cc = c < 3 ? c : 2;              // clamp for safe read
        xOff[j] = cc * 408 + dy * 34 + dx;
        kMask[j] = (c < 3) ? 0xFFFF : 0;
        kOvr[j]  = (c < 3) ? 0 : (k == 27 ? 0x3F80 : 0);
    }
    __syncthreads();

    const short* stSrc = w2c + t * 8;         // staging source base (kk=0 half)
    short* stDst = (short*)bufB + t * 8;      // staging dest base

    // issue LDS-half stage for steps 0,1 now; latency hides under phase A;
    // the phase A->B __syncthreads (full vmcnt drain) is the completion point.
    gl_lds16(stSrc, stDst);                   // st0 kk=0 half
    gl_lds16(stSrc + 4096, stDst + 2048);     // st1 kk=0 half

    // ---- phase A: conv1 -> c1t. 20 pos-tiles of 16 (10 rows x 32 cols);
    //      wave w -> tiles 5w..5w+4. weights = A-operand, x patch = B. ----
#pragma unroll 1
    for (int pt = 0; pt < 5; ++pt) {
        const int tile = w * 5 + pt;
        const int r = tile >> 1, xcb = (tile & 1) << 4;
        const int baseA = r * 34 + xcb + ln15;
        bfrag a1f;                            // x patch (B-operand)
#pragma unroll
        for (int j = 0; j < 8; ++j)
            a1f[j] = (short)((xt[xOff[j] + baseA] & kMask[j]) | kOvr[j]);
        f32x4 acc1[4];
#pragma unroll
        for (int ot = 0; ot < 4; ++ot) {
#pragma unroll
            for (int rg = 0; rg < 4; ++rg) acc1[ot][rg] = 0.f;
            acc1[ot] = __builtin_amdgcn_mfma_f32_16x16x32_bf16(
                b1f[ot], a1f, acc1[ot], 0, 0, 0);
        }
        // D: row = oc (ot*16 + (lane>>4)*4 + rg), col = pos (tile*16 + ln15).
        const int y = band * 8 - 1 + r;
        const bool valid = (unsigned)y < 32u;    // wave-uniform
        const int waddr = (r * 34 + xcb + ln15 + 1) * 72 + (lane >> 4) * 4;
#pragma unroll
        for (int ot = 0; ot < 4; ++ot) {
            uint2 pk = {0u, 0u};
            if (valid) {
                pk.x = cvtpk(fmaxf(acc1[ot][0], 0.f), fmaxf(acc1[ot][1], 0.f));
                pk.y = cvtpk(fmaxf(acc1[ot][2], 0.f), fmaxf(acc1[ot][3], 0.f));
            }
            *(uint2*)&c1t[waddr + ot * 16] = pk;
        }
    }
    __syncthreads();   // c1t ready + bufB st0/st1 staged (full vmcnt drain)

    // ---- phase B: conv2, 32x32x16 MFMA. wave = 2 rows x 32 cols x 128 oc ----
    float b2v[4];
#pragma unroll
    for (int ot = 0; ot < 4; ++ot) b2v[ot] = b2[ot * 32 + ln31];

    f32x16 acc[2][4];
#pragma unroll
    for (int pt = 0; pt < 2; ++pt)
#pragma unroll
        for (int ot = 0; ot < 4; ++ot)
#pragma unroll
            for (int rg = 0; rg < 16; ++rg) acc[pt][ot][rg] = 0.f;

    // A-frag 32x32x16: row = lane&31 (image col), k = (lane>>5)*8 + j (ic)
    const int aB0 = (w * 2 * 34 + ln31) * 72 + hi * 8;
    const int aB1 = aB0 + 34 * 72;
    const int bOff = hi * 1024 + ln31 * 8;    // within a 2048-short half-chunk

    auto stage = [&](int st) {                // kk=0 half (4KB) -> buf st%3
        gl_lds16(stSrc + st * 4096, stDst + (st % 3) * 2048);
    };
    auto loadBG = [&](bfrag* bg, int st) {    // kk=1 half -> regs (4 dwordx4)
        const short* p = w2c + st * 4096 + 2048 + bOff;
#pragma unroll
        for (int ot = 0; ot < 4; ++ot) bg[ot] = *(const bfrag*)(p + ot * 256);
    };
    auto body = [&](int st, const bfrag* bgc, bfrag* bgn) {
        if (st + 2 < 18) stage(st + 2);
        if (st + 1 < 18) loadBG(bgn, st + 1);  // completes under next body
        const int tap = st >> 1, kh = st & 1;
        const int dy = (tap * 11) >> 5, dx = tap - 3 * dy;
        const int aOff = (dy * 34 + dx) * 72 + kh * 32;
        bfrag af0 = *(const bfrag*)&c1t[aB0 + aOff];        // kk=0, row0
        bfrag af1 = *(const bfrag*)&c1t[aB0 + aOff + 16];   // kk=1, row0
        bfrag af2 = *(const bfrag*)&c1t[aB1 + aOff];        // kk=0, row1
        bfrag af3 = *(const bfrag*)&c1t[aB1 + aOff + 16];   // kk=1, row1
        const short* bl = (const short*)bufB + (st % 3) * 2048 + bOff;
        bfrag bl0 = *(const bfrag*)(bl);
        bfrag bl1 = *(const bfrag*)(bl + 256);
        bfrag bl2 = *(const bfrag*)(bl + 512);
        bfrag bl3 = *(const bfrag*)(bl + 768);
        __builtin_amdgcn_s_setprio(1);
        // kk=1 (global-half B, regs ready from last body)
        acc[0][0] = __builtin_amdgcn_mfma_f32_32x32x16_bf16(af1, bgc[0], acc[0][0], 0, 0, 0);
        acc[0][1] = __builtin_amdgcn_mfma_f32_32x32x16_bf16(af1, bgc[1], acc[0][1], 0, 0, 0);
        acc[0][2] = __builtin_amdgcn_mfma_f32_32x32x16_bf16(af1, bgc[2], acc[0][2], 0, 0, 0);
        acc[0][3] = __builtin_amdgcn_mfma_f32_32x32x16_bf16(af1, bgc[3], acc[0][3], 0, 0, 0);
        acc[1][0] = __builtin_amdgcn_mfma_f32_32x32x16_bf16(af3, bgc[0], acc[1][0], 0, 0, 0);
        acc[1][1] = __builtin_amdgcn_mfma_f32_32x32x16_bf16(af3, bgc[1], acc[1][1], 0, 0, 0);
        acc[1][2] = __builtin_amdgcn_mfma_f32_32x32x16_bf16(af3, bgc[2], acc[1][2], 0, 0, 0);
        acc[1][3] = __builtin_amdgcn_mfma_f32_32x32x16_bf16(af3, bgc[3], acc[1][3], 0, 0, 0);
        // kk=0 (LDS-half B, ds_reads above complete during kk=1 block)
        acc[0][0] = __builtin_amdgcn_mfma_f32_32x32x16_bf16(af0, bl0, acc[0][0], 0, 0, 0);
        acc[0][1] = __builtin_amdgcn_mfma_f32_32x32x16_bf16(af0, bl1, acc[0][1], 0, 0, 0);
        acc[0][2] = __builtin_amdgcn_mfma_f32_32x32x16_bf16(af0, bl2, acc[0][2], 0, 0, 0);
        acc[0][3] = __builtin_amdgcn_mfma_f32_32x32x16_bf16(af0, bl3, acc[0][3], 0, 0, 0);
        acc[1][0] = __builtin_amdgcn_mfma_f32_32x32x16_bf16(af2, bl0, acc[1][0], 0, 0, 0);
        acc[1][1] = __builtin_amdgcn_mfma_f32_32x32x16_bf16(af2, bl1, acc[1][1], 0, 0, 0);
        acc[1][2] = __builtin_amdgcn_mfma_f32_32x32x16_bf16(af2, bl2, acc[1][2], 0, 0, 0);
        acc[1][3] = __builtin_amdgcn_mfma_f32_32x32x16_bf16(af2, bl3, acc[1][3], 0, 0, 0);
        __builtin_amdgcn_s_setprio(0);
        // counted wait: drain THIS body's stage (oldest of the <=5 in flight)
        // so after the barrier all waves may read buf[(st+2)%3] next bodies;
        // the 4 loadBG(st+1) prefetches stay in flight across the barrier.
        if (st < 16) { asm volatile("s_waitcnt vmcnt(4)" ::: "memory"); }
        else         { asm volatile("s_waitcnt vmcnt(0)" ::: "memory"); }
        __builtin_amdgcn_s_barrier();
    };

    bfrag bGX[4], bGY[4];
    loadBG(bGX, 0);
#pragma unroll 1
    for (int st = 0; st < 18; st += 2) {      // X/Y shadow-reg pipeline
        body(st, bGX, bGY);
        body(st + 1, bGY, bGX);
    }

    // bias + relu + pool. 32x32 C/D: col(lane&31)=oc, rows spread over
    // regs & half-wave -> per-lane partial covers 16 of 32 rows; xor 32.
#pragma unroll
    for (int ot = 0; ot < 4; ++ot) {
        float s = 0.f;
#pragma unroll
        for (int pt = 0; pt < 2; ++pt)
#pragma unroll
            for (int rg = 0; rg < 16; ++rg)
                s += fmaxf(acc[pt][ot][rg] + b2v[ot], 0.f);
        s += __shfl_xor(s, 32, 64);
        if (lane < 32) wsum[w][ot * 32 + ln31] = s;
    }
    __syncthreads();
    if (t < 128) {
        pooled4[((size_t)img * 4 + band) * 128 + t] =
            wsum[0][t] + wsum[1][t] + wsum[2][t] + wsum[3][t];
    }
}

// fc: grid 1024 (one block per image) -- wide grid hides weight-load latency.
__global__ __launch_bounds__(256) void fc_kernel(
    const float* __restrict__ pooled4, const float* __restrict__ fwT,
    const float* __restrict__ fb, const float* __restrict__ mask,
    float* __restrict__ z1) {
    const int img = blockIdx.x;
    __shared__ float m[128];
    const int t = threadIdx.x;
    if (t < 128) {
        const float* p = pooled4 + (size_t)img * 4 * 128 + t;
        m[t] = (p[0] + p[128] + p[256] + p[384]) * (1.f / 1024.f);
    }
    __syncthreads();
    float acc = fb[t];
#pragma unroll 4
    for (int c = 0; c < 128; ++c) acc = fmaf(m[c], fwT[c * 256 + t], acc);  // coalesced
    z1[img * 256 + t] = acc * mask[img];
}

// sage1+relu: grid 256 = (bb, chunk of 4 nodes); thread t = output o.
__global__ __launch_bounds__(256) void sage1_kernel(
    const float* __restrict__ z1, const float* __restrict__ l1T,
    const float* __restrict__ lb, const float* __restrict__ w1pT,
    float* __restrict__ z2) {
    const int bb = blockIdx.x >> 3, chunk = blockIdx.x & 7;
    __shared__ float h[32 * 256];
    __shared__ float sl[256];
    const int t = threadIdx.x;
    const float* zb = z1 + bb * 8192;
    for (int idx = t; idx < 8192; idx += 256) h[idx] = zb[idx];
    __syncthreads();
    float s = 0.f;
#pragma unroll
    for (int n = 0; n < 32; ++n) s += h[n * 256 + t];
    sl[t] = s * (1.f / 31.f);
    __syncthreads();
    float c = lb[t];
#pragma unroll 4
    for (int d = 0; d < 256; ++d) c = fmaf(sl[d], l1T[d * 256 + t], c);
    float acc[4];
#pragma unroll
    for (int i = 0; i < 4; ++i) acc[i] = c;
    for (int d0 = 0; d0 < 256; d0 += 4) {
        float wv0 = w1pT[(d0 + 0) * 256 + t];
        float wv1 = w1pT[(d0 + 1) * 256 + t];
        float wv2 = w1pT[(d0 + 2) * 256 + t];
        float wv3 = w1pT[(d0 + 3) * 256 + t];
#pragma unroll
        for (int i = 0; i < 4; ++i) {
            f32x4 hv = *(const f32x4*)&h[(chunk * 4 + i) * 256 + d0];  // LDS broadcast
            acc[i] = fmaf(hv[0], wv0, acc[i]);
            acc[i] = fmaf(hv[1], wv1, acc[i]);
            acc[i] = fmaf(hv[2], wv2, acc[i]);
            acc[i] = fmaf(hv[3], wv3, acc[i]);
        }
    }
    for (int i = 0; i < 4; ++i)
        z2[(bb * 32 + chunk * 4 + i) * 256 + t] = fmaxf(acc[i], 0.f);
}

// sage2: grid 256 = (bb, chunk of 4 nodes); o = t&127, half = t>>7 (2 nodes each).
__global__ __launch_bounds__(256) void sage2_kernel(
    const float* __restrict__ z2, const float* __restrict__ l2T,
    const float* __restrict__ lb, const float* __restrict__ w2pT,
    float* __restrict__ out) {
    const int bb = blockIdx.x >> 3, chunk = blockIdx.x & 7;
    __shared__ float h[32 * 256];
    __shared__ float sl[256];
    const int t = threadIdx.x;
    const float* zb = z2 + bb * 8192;
    for (int idx = t; idx < 8192; idx += 256) h[idx] = zb[idx];
    __syncthreads();
    float s = 0.f;
#pragma unroll
    for (int n = 0; n < 32; ++n) s += h[n * 256 + t];
    sl[t] = s * (1.f / 31.f);
    __syncthreads();
    const int o = t & 127, half = t >> 7;
    float c = lb[o];
#pragma unroll 4
    for (int d = 0; d < 256; ++d) c = fmaf(sl[d], l2T[d * 128 + o], c);
    float acc[2];
    acc[0] = c; acc[1] = c;
    const int n0 = chunk * 4 + half * 2;
    for (int d0 = 0; d0 < 256; d0 += 4) {
        float wv0 = w2pT[(d0 + 0) * 128 + o];
        float wv1 = w2pT[(d0 + 1) * 128 + o];
        float wv2 = w2pT[(d0 + 2) * 128 + o];
        float wv3 = w2pT[(d0 + 3) * 128 + o];
#pragma unroll
        for (int ii = 0; ii < 2; ++ii) {
            f32x4 hv = *(const f32x4*)&h[(n0 + ii) * 256 + d0];
            acc[ii] = fmaf(hv[0], wv0, acc[ii]);
            acc[ii] = fmaf(hv[1], wv1, acc[ii]);
            acc[ii] = fmaf(hv[2], wv2, acc[ii]);
            acc[ii] = fmaf(hv[3], wv3, acc[ii]);
        }
    }
    for (int ii = 0; ii < 2; ++ii)
        out[(size_t)(bb * 32 + n0 + ii) * 128 + o] = acc[ii];
}

extern "C" void kernel_launch(void* const* d_in, const int* in_sizes, int n_in,
                              void* d_out, int out_size, void* d_ws, size_t ws_size,
                              hipStream_t stream) {
    const float* x    = (const float*)d_in[0];
    const float* mask = (const float*)d_in[1];
    const float* c1w  = (const float*)d_in[2];
    const float* c1b  = (const float*)d_in[3];
    const float* c2w  = (const float*)d_in[4];
    const float* c2b  = (const float*)d_in[5];
    const float* fcw  = (const float*)d_in[6];
    const float* fcb  = (const float*)d_in[7];
    const float* s1lw = (const float*)d_in[8];
    const float* s1lb = (const float*)d_in[9];
    const float* s1rw = (const float*)d_in[10];
    const float* s2lw = (const float*)d_in[11];
    const float* s2lb = (const float*)d_in[12];
    const float* s2rw = (const float*)d_in[13];
    float* out = (float*)d_out;

    char* ws = (char*)d_ws;
    float* pooled4 = (float*)(ws);
    float* z1      = (float*)(ws + 2048u * 1024);
    float* z2      = (float*)(ws + 3072u * 1024);
    float* l1T     = (float*)(ws + 4096u * 1024);
    float* w1pT    = (float*)(ws + 4352u * 1024);
    float* l2T     = (float*)(ws + 4608u * 1024);
    float* w2pT    = (float*)(ws + 4736u * 1024);
    float* fwT     = (float*)(ws + 4864u * 1024);
    short* w2c     = (short*)(ws + 4992u * 1024);
    short* w1b     = (short*)(ws + 5136u * 1024);

    prep_kernel<<<dim3(288), 256, 0, stream>>>(s1lw, s1rw, s2lw, s2rw, c2w, c1w, c1b,
                                               fcw, l1T, w1pT, l2T, w2pT, fwT, w2c, w1b);
    fused_conv_kernel<<<dim3(4, 1024), 256, 0, stream>>>(x, w1b, w2c, c2b, pooled4);
    fc_kernel<<<dim3(1024), 256, 0, stream>>>(pooled4, fwT, fcb, mask, z1);
    sage1_kernel<<<dim3(256), 256, 0, stream>>>(z1, l1T, s1lb, w1pT, z2);
    sage2_kernel<<<dim3(256), 256, 0, stream>>>(z2, l2T, s2lb, w2pT, out);
}

// Round 7
// 258.877 us; speedup vs baseline: 1.6952x; 1.1350x over previous
//
#include <hip/hip_runtime.h>
#include <hip/hip_bf16.h>

// x:[1024,3,32,32] -> conv1(3->64)+relu -> conv2(64->128)+relu -> meanpool
// -> fc(128->256)+b -> *mask -> sage1(256->256)+relu -> sage2(256->128)
// Output [32,32,128] fp32.
//
// Workspace layout (<6MB):
//  [0,2M)        pooled4 [1024][4][128] f32 (band partials, pre-divide)
//  [2M,3M)       z1 [1024][256]
//  [3M,4M)       z2 [1024][256]
//  [4096K,+256K) l1T  [256][256] = s1lw^T
//  [4352K,+256K) w1pT [256][256] = (s1rw - s1lw/31)^T
//  [4608K,+128K) l2T  [256][128] = s2lw^T
//  [4736K,+128K) w2pT [256][128] = (s2rw - s2lw/31)^T
//  [4864K,+128K) fwT  [128][256] = fc_w^T
//  [4992K,+144K) w2c  [9][4][2][128][8] bf16 conv2 w: [tap][ks][hi][oc][j],
//                ic = ks*16 + hi*8 + j  (B-frag order for 32x32x16 MFMA)
//  [5136K,+4K)   w1b  [64][32] bf16 conv1 w+bias (k=27 slot = bias)

typedef __attribute__((ext_vector_type(8))) short bfrag;
typedef __attribute__((ext_vector_type(4))) float f32x4;
typedef __attribute__((ext_vector_type(16))) float f32x16;

static __device__ __forceinline__ unsigned short f2bf(float f) {
    union { float f; unsigned u; } v; v.f = f;
    unsigned r = v.u + 0x7fff + ((v.u >> 16) & 1);   // RNE (finite)
    return (unsigned short)(r >> 16);
}

// pack two f32 -> two bf16 (RNE) in one instr
static __device__ __forceinline__ unsigned cvtpk(float lo, float hi) {
    unsigned r;
    asm("v_cvt_pk_bf16_f32 %0, %1, %2" : "=v"(r) : "v"(lo), "v"(hi));
    return r;
}

// async global->LDS, 16B per lane (linear dest = wave-uniform base + lane*16)
static __device__ __forceinline__ void gl_lds16(const short* g, short* l) {
    __builtin_amdgcn_global_load_lds(
        (const __attribute__((address_space(1))) unsigned int*)g,
        (__attribute__((address_space(3))) unsigned int*)l, 16, 0, 0);
}

__global__ __launch_bounds__(256) void prep_kernel(
    const float* __restrict__ s1lw, const float* __restrict__ s1rw,
    const float* __restrict__ s2lw, const float* __restrict__ s2rw,
    const float* __restrict__ c2w, const float* __restrict__ c1w,
    const float* __restrict__ c1b, const float* __restrict__ fcw,
    float* __restrict__ l1T, float* __restrict__ w1pT,
    float* __restrict__ l2T, float* __restrict__ w2pT,
    float* __restrict__ fwT,
    short* __restrict__ w2c, short* __restrict__ w1b) {
    int i = blockIdx.x * 256 + threadIdx.x;     // grid 288 -> [0, 73728)
    const float inv31 = 1.f / 31.f;
    if (i < 65536) {
        int d = i >> 8, o = i & 255;
        float lw = s1lw[o * 256 + d];
        l1T[i]  = lw;
        w1pT[i] = s1rw[o * 256 + d] - lw * inv31;
    }
    if (i < 32768) {
        int d = i >> 7, o = i & 127;
        float lw = s2lw[o * 256 + d];
        l2T[i]  = lw;
        w2pT[i] = s2rw[o * 256 + d] - lw * inv31;
        int c = i >> 8, o2 = i & 255;
        fwT[i] = fcw[o2 * 128 + c];
    }
    if (i < 73728) {        // w2c[tap][ks][hi][oc][j] = c2w[oc][ic][tap]
        int tap = i >> 13, r = i & 8191;
        int ks = r >> 11, hi = (r >> 10) & 1, oc = (r >> 3) & 127, j = i & 7;
        int ic = ks * 16 + hi * 8 + j;
        w2c[i] = (short)f2bf(c2w[(oc * 64 + ic) * 9 + tap]);
    }
    if (i < 2048) {                             // w1b[oc][k], k=27 -> bias
        int oc = i >> 5, k = i & 31;
        float v = (k < 27) ? c1w[oc * 27 + k] : (k == 27 ? c1b[oc] : 0.f);
        w1b[i] = (short)f2bf(v);
    }
}

// Fused conv1+conv2+pool: grid (4 bands of 8 rows, 1024 imgs).
// R7: reverted verbatim to R4 (best measured 161-164us). R1/R3/R4/R6 all fit
// a SUM-of-pipes model (not max): with 2 waves/SIMD the per-wave serial
// {read, wait, MFMA} chains don't cross-hide. Conv is parked at this plateau;
// this round optimizes the ~120us kernel tail instead.
__global__ __launch_bounds__(256, 2) void fused_conv_kernel(
    const float* __restrict__ x, const short* __restrict__ w1b,
    const short* __restrict__ w2c, const float* __restrict__ b2,
    float* __restrict__ pooled4) {
    const int band = blockIdx.x, img = blockIdx.y;
    __shared__ short xt[3 * 12 * 34];     // 2448 B: input rows band*8-2..band*8+9
    __shared__ short c1t[10 * 34 * 72];   // 48960 B [row][col pad34][ic pad72]
    __shared__ short bufB[3][4096];       // 24576 B: 3 x 8KB K-step chunks of w2c
    __shared__ float wsum[4][128];
    const int t = threadIdx.x;
    const int w = t >> 6, lane = t & 63;
    const int ln15 = lane & 15, q8 = (lane >> 4) * 8;
    const int ln31 = lane & 31, hi = lane >> 5;

    // stage xt (zero-padded), zero c1t pad cols 0/33
    const float* xi = x + img * 3072;
    for (int idx = t; idx < 1224; idx += 256) {
        int c = idx / 408, rem = idx % 408, r = rem / 34, col = rem % 34;
        int y = band * 8 - 2 + r, xx = col - 1;
        float v = 0.f;
        if ((unsigned)y < 32u && (unsigned)xx < 32u) v = xi[c * 1024 + y * 32 + xx];
        xt[idx] = (short)f2bf(v);
    }
    {
        f32x4 z = {0.f, 0.f, 0.f, 0.f};
        for (int i = t; i < 180; i += 256) {          // 10r x 2c x 9 f32x4
            int r = i / 18, rem = i % 18, side = rem / 9, q = rem % 9;
            *(f32x4*)(c1t + (r * 34 + side * 33) * 72 + q * 8) = z;
        }
    }
    bfrag b1f[4];
#pragma unroll
    for (int ot = 0; ot < 4; ++ot)
        b1f[ot] = *(const bfrag*)(w1b + (ot * 16 + ln15) * 32 + q8);

    // hoisted per-lane conv1 tap decomposition (invariant over pos tiles)
    int xOff[8]; int kMask[8]; int kOvr[8];
#pragma unroll
    for (int j = 0; j < 8; ++j) {
        int k = q8 + j;
        int c = (k * 57) >> 9;               // k/9 for k<36
        int rem = k - 9 * c;
        int dy = (rem * 11) >> 5;            // rem/3 for rem<9
        int dx = rem - 3 * dy;
        int cc = c < 3 ? c : 2;              // clamp for safe read
        xOff[j] = cc * 408 + dy * 34 + dx;
        kMask[j] = (c < 3) ? 0xFFFF : 0;
        kOvr[j]  = (c < 3) ? 0 : (k == 27 ? 0x3F80 : 0);
    }
    __syncthreads();

    // issue B stage for steps 0,1 now; latency hides under phase A; the
    // phase A->B __syncthreads (full vmcnt drain) is the completion point.
    {
        const short* src = w2c + t * 8;
        short* dst = (short*)bufB + t * 8;
        gl_lds16(src, dst);                   // st0 lo half
        gl_lds16(src + 2048, dst + 2048);     // st0 hi half
        gl_lds16(src + 4096, dst + 4096);     // st1 lo half
        gl_lds16(src + 6144, dst + 6144);     // st1 hi half
    }

    // ---- phase A: conv1 -> c1t. 20 pos-tiles of 16 (10 rows x 32 cols);
    //      wave w -> tiles 5w..5w+4. weights = A-operand, x patch = B. ----
#pragma unroll 1
    for (int pt = 0; pt < 5; ++pt) {
        const int tile = w * 5 + pt;
        const int r = tile >> 1, xcb = (tile & 1) << 4;
        const int baseA = r * 34 + xcb + ln15;
        bfrag a1f;                            // x patch (B-operand)
#pragma unroll
        for (int j = 0; j < 8; ++j)
            a1f[j] = (short)((xt[xOff[j] + baseA] & kMask[j]) | kOvr[j]);
        f32x4 acc1[4];
#pragma unroll
        for (int ot = 0; ot < 4; ++ot) {
#pragma unroll
            for (int rg = 0; rg < 4; ++rg) acc1[ot][rg] = 0.f;
            acc1[ot] = __builtin_amdgcn_mfma_f32_16x16x32_bf16(
                b1f[ot], a1f, acc1[ot], 0, 0, 0);
        }
        // D: row = oc (ot*16 + (lane>>4)*4 + rg), col = pos (tile*16 + ln15).
        const int y = band * 8 - 1 + r;
        const bool valid = (unsigned)y < 32u;    // wave-uniform
        const int waddr = (r * 34 + xcb + ln15 + 1) * 72 + (lane >> 4) * 4;
#pragma unroll
        for (int ot = 0; ot < 4; ++ot) {
            uint2 pk = {0u, 0u};
            if (valid) {
                pk.x = cvtpk(fmaxf(acc1[ot][0], 0.f), fmaxf(acc1[ot][1], 0.f));
                pk.y = cvtpk(fmaxf(acc1[ot][2], 0.f), fmaxf(acc1[ot][3], 0.f));
            }
            *(uint2*)&c1t[waddr + ot * 16] = pk;
        }
    }
    __syncthreads();   // c1t ready + bufB st0/st1 staged (full vmcnt drain)

    // ---- phase B: conv2, 32x32x16 MFMA. wave = 2 rows x 32 cols x 128 oc ----
    float b2v[4];
#pragma unroll
    for (int ot = 0; ot < 4; ++ot) b2v[ot] = b2[ot * 32 + ln31];

    f32x16 acc[2][4];
#pragma unroll
    for (int pt = 0; pt < 2; ++pt)
#pragma unroll
        for (int ot = 0; ot < 4; ++ot)
#pragma unroll
            for (int rg = 0; rg < 16; ++rg) acc[pt][ot][rg] = 0.f;

    // A-frag 32x32x16: row = lane&31 (image col), k = (lane>>5)*8 + j (ic)
    const int aB0 = (w * 2 * 34 + ln31) * 72 + hi * 8;
    const int aB1 = aB0 + 34 * 72;
    const int bOff = hi * 1024 + ln31 * 8;    // within an 8KB step chunk
    const short* stSrc = w2c + t * 8;         // staging source base
    short* stDst = (short*)bufB + t * 8;      // staging dest base

    auto stage = [&](int st) {                // 8KB step chunk -> buf st%3
        const short* src = stSrc + st * 4096;
        short* dst = stDst + (st % 3) * 4096;
        gl_lds16(src, dst);
        gl_lds16(src + 2048, dst + 2048);
    };
    auto prefB = [&](bfrag* bf, int st) {     // B-frags for step st from LDS
        const short* bc = (const short*)bufB + (st % 3) * 4096 + bOff;
#pragma unroll
        for (int kk = 0; kk < 2; ++kk)
#pragma unroll
            for (int ot = 0; ot < 4; ++ot)
                bf[kk * 4 + ot] = *(const bfrag*)(bc + kk * 2048 + ot * 256);
    };
    auto body = [&](int st, const bfrag* bCur, bfrag* bNext) {
        if (st + 2 < 18) stage(st + 2);
        const int tap = st >> 1, kh = st & 1;
        const int dy = (tap * 11) >> 5, dx = tap - 3 * dy;
        const int aOff = (dy * 34 + dx) * 72 + kh * 32;
        bfrag af0 = *(const bfrag*)&c1t[aB0 + aOff];   // af first: first MFMA
        bfrag af1 = *(const bfrag*)&c1t[aB0 + aOff + 16];  // waits only af0
        bfrag af2 = *(const bfrag*)&c1t[aB1 + aOff];
        bfrag af3 = *(const bfrag*)&c1t[aB1 + aOff + 16];
        if (st + 1 < 18) prefB(bNext, st + 1);   // completes under MFMAs
        __builtin_amdgcn_s_setprio(1);
#pragma unroll
        for (int ot = 0; ot < 4; ++ot)
            acc[0][ot] = __builtin_amdgcn_mfma_f32_32x32x16_bf16(
                af0, bCur[ot], acc[0][ot], 0, 0, 0);
#pragma unroll
        for (int ot = 0; ot < 4; ++ot)
            acc[0][ot] = __builtin_amdgcn_mfma_f32_32x32x16_bf16(
                af1, bCur[4 + ot], acc[0][ot], 0, 0, 0);
#pragma unroll
        for (int ot = 0; ot < 4; ++ot)
            acc[1][ot] = __builtin_amdgcn_mfma_f32_32x32x16_bf16(
                af2, bCur[ot], acc[1][ot], 0, 0, 0);
#pragma unroll
        for (int ot = 0; ot < 4; ++ot)
            acc[1][ot] = __builtin_amdgcn_mfma_f32_32x32x16_bf16(
                af3, bCur[4 + ot], acc[1][ot], 0, 0, 0);
        __builtin_amdgcn_s_setprio(0);
        // drain own stage(st+2) (issued ~600cyc ago) so after the barrier all
        // waves may read buf[(st+2)%3]'s predecessor-free data next body.
        asm volatile("s_waitcnt vmcnt(0)" ::: "memory");
        __builtin_amdgcn_s_barrier();
    };

    bfrag bX[8], bY[8];
    prefB(bX, 0);                             // buf0/buf1 complete (syncthreads)
#pragma unroll 1
    for (int st = 0; st < 18; st += 2) {      // X/Y shadow-reg pipeline
        body(st, bX, bY);
        body(st + 1, bY, bX);
    }

    // bias + relu + pool. 32x32 C/D: col(lane&31)=oc, rows spread over
    // regs & half-wave -> per-lane partial covers 16 of 32 rows; xor 32.
#pragma unroll
    for (int ot = 0; ot < 4; ++ot) {
        float s = 0.f;
#pragma unroll
        for (int pt = 0; pt < 2; ++pt)
#pragma unroll
            for (int rg = 0; rg < 16; ++rg)
                s += fmaxf(acc[pt][ot][rg] + b2v[ot], 0.f);
        s += __shfl_xor(s, 32, 64);
        if (lane < 32) wsum[w][ot * 32 + ln31] = s;
    }
    __syncthreads();
    if (t < 128) {
        pooled4[((size_t)img * 4 + band) * 128 + t] =
            wsum[0][t] + wsum[1][t] + wsum[2][t] + wsum[3][t];
    }
}

// fc: grid 1024 (one block per image) -- wide grid hides weight-load latency.
__global__ __launch_bounds__(256) void fc_kernel(
    const float* __restrict__ pooled4, const float* __restrict__ fwT,
    const float* __restrict__ fb, const float* __restrict__ mask,
    float* __restrict__ z1) {
    const int img = blockIdx.x;
    __shared__ float m[128];
    const int t = threadIdx.x;
    if (t < 128) {
        const float* p = pooled4 + (size_t)img * 4 * 128 + t;
        m[t] = (p[0] + p[128] + p[256] + p[384]) * (1.f / 1024.f);
    }
    __syncthreads();
    float acc = fb[t];
#pragma unroll 4
    for (int c = 0; c < 128; ++c) acc = fmaf(m[c], fwT[c * 256 + t], acc);  // coalesced
    z1[img * 256 + t] = acc * mask[img];
}

// sage1+relu v2: grid 512 = (bb 32, chunk 8, ohalf 2). Block = 4 nodes x 128
// outputs x 2 d-halves (256 thr). R7: prior version was 256 blocks = 1/CU
// with a serial 256-iter chain; d-split halves the chain AND doubles the grid
// (2 blocks/CU) -> latency overlaps. Weight traffic unchanged (L2-served).
__global__ __launch_bounds__(256) void sage1_kernel(
    const float* __restrict__ z1, const float* __restrict__ l1T,
    const float* __restrict__ lb, const float* __restrict__ w1pT,
    float* __restrict__ z2) {
    const int bx = blockIdx.x;
    const int bb = bx >> 4, chunk = (bx >> 1) & 7, ohalf = bx & 1;
    __shared__ float h[32 * 256];
    __shared__ float sl[256];
    __shared__ float part[2][128];
    __shared__ float pacc[2][4][128];
    const int t = threadIdx.x;
    const int oo = t & 127, dh = t >> 7;
    const int o = ohalf * 128 + oo;
    const float* zb = z1 + bb * 8192;
    for (int idx = t; idx < 8192; idx += 256) h[idx] = zb[idx];
    __syncthreads();
    {
        float s = 0.f;
#pragma unroll
        for (int n = 0; n < 32; ++n) s += h[n * 256 + t];
        sl[t] = s * (1.f / 31.f);
    }
    __syncthreads();
    const int d0b = dh * 128;
    float c = 0.f;
#pragma unroll 4
    for (int d = 0; d < 128; ++d) c = fmaf(sl[d0b + d], l1T[(d0b + d) * 256 + o], c);
    part[dh][oo] = c;
    float acc[4] = {0.f, 0.f, 0.f, 0.f};
    for (int d = 0; d < 128; d += 4) {
        float wv0 = w1pT[(d0b + d + 0) * 256 + o];
        float wv1 = w1pT[(d0b + d + 1) * 256 + o];
        float wv2 = w1pT[(d0b + d + 2) * 256 + o];
        float wv3 = w1pT[(d0b + d + 3) * 256 + o];
#pragma unroll
        for (int i = 0; i < 4; ++i) {
            f32x4 hv = *(const f32x4*)&h[(chunk * 4 + i) * 256 + d0b + d];
            acc[i] = fmaf(hv[0], wv0, acc[i]);
            acc[i] = fmaf(hv[1], wv1, acc[i]);
            acc[i] = fmaf(hv[2], wv2, acc[i]);
            acc[i] = fmaf(hv[3], wv3, acc[i]);
        }
    }
#pragma unroll
    for (int i = 0; i < 4; ++i) pacc[dh][i][oo] = acc[i];
    __syncthreads();
    const float cf = part[0][oo] + part[1][oo] + lb[o];
#pragma unroll
    for (int ii = 0; ii < 2; ++ii) {
        const int i = dh * 2 + ii;
        float v = cf + pacc[0][i][oo] + pacc[1][i][oo];
        z2[(bb * 32 + chunk * 4 + i) * 256 + o] = fmaxf(v, 0.f);
    }
}

// sage2 v2: grid 512 = (bb 32, chunk 16). Block = 2 nodes x 128 outputs x 2
// d-halves (256 thr). Same d-split rationale as sage1.
__global__ __launch_bounds__(256) void sage2_kernel(
    const float* __restrict__ z2, const float* __restrict__ l2T,
    const float* __restrict__ lb, const float* __restrict__ w2pT,
    float* __restrict__ out) {
    const int bx = blockIdx.x;
    const int bb = bx >> 4, chunk = bx & 15;
    __shared__ float h[32 * 256];
    __shared__ float sl[256];
    __shared__ float part[2][128];
    __shared__ float pacc[2][2][128];
    const int t = threadIdx.x;
    const int oo = t & 127, dh = t >> 7;
    const float* zb = z2 + bb * 8192;
    for (int idx = t; idx < 8192; idx += 256) h[idx] = zb[idx];
    __syncthreads();
    {
        float s = 0.f;
#pragma unroll
        for (int n = 0; n < 32; ++n) s += h[n * 256 + t];
        sl[t] = s * (1.f / 31.f);
    }
    __syncthreads();
    const int d0b = dh * 128;
    const int n0 = chunk * 2;
    float c = 0.f;
#pragma unroll 4
    for (int d = 0; d < 128; ++d) c = fmaf(sl[d0b + d], l2T[(d0b + d) * 128 + oo], c);
    part[dh][oo] = c;
    float acc[2] = {0.f, 0.f};
    for (int d = 0; d < 128; d += 4) {
        float wv0 = w2pT[(d0b + d + 0) * 128 + oo];
        float wv1 = w2pT[(d0b + d + 1) * 128 + oo];
        float wv2 = w2pT[(d0b + d + 2) * 128 + oo];
        float wv3 = w2pT[(d0b + d + 3) * 128 + oo];
#pragma unroll
        for (int i = 0; i < 2; ++i) {
            f32x4 hv = *(const f32x4*)&h[(n0 + i) * 256 + d0b + d];
            acc[i] = fmaf(hv[0], wv0, acc[i]);
            acc[i] = fmaf(hv[1], wv1, acc[i]);
            acc[i] = fmaf(hv[2], wv2, acc[i]);
            acc[i] = fmaf(hv[3], wv3, acc[i]);
        }
    }
#pragma unroll
    for (int i = 0; i < 2; ++i) pacc[dh][i][oo] = acc[i];
    __syncthreads();
    const float cf = part[0][oo] + part[1][oo] + lb[oo];
    {
        const int i = dh;    // 256 threads = 2 nodes x 128 outputs
        float v = cf + pacc[0][i][oo] + pacc[1][i][oo];
        out[(size_t)(bb * 32 + n0 + i) * 128 + oo] = v;
    }
}

extern "C" void kernel_launch(void* const* d_in, const int* in_sizes, int n_in,
                              void* d_out, int out_size, void* d_ws, size_t ws_size,
                              hipStream_t stream) {
    const float* x    = (const float*)d_in[0];
    const float* mask = (const float*)d_in[1];
    const float* c1w  = (const float*)d_in[2];
    const float* c1b  = (const float*)d_in[3];
    const float* c2w  = (const float*)d_in[4];
    const float* c2b  = (const float*)d_in[5];
    const float* fcw  = (const float*)d_in[6];
    const float* fcb  = (const float*)d_in[7];
    const float* s1lw = (const float*)d_in[8];
    const float* s1lb = (const float*)d_in[9];
    const float* s1rw = (const float*)d_in[10];
    const float* s2lw = (const float*)d_in[11];
    const float* s2lb = (const float*)d_in[12];
    const float* s2rw = (const float*)d_in[13];
    float* out = (float*)d_out;

    char* ws = (char*)d_ws;
    float* pooled4 = (float*)(ws);
    float* z1      = (float*)(ws + 2048u * 1024);
    float* z2      = (float*)(ws + 3072u * 1024);
    float* l1T     = (float*)(ws + 4096u * 1024);
    float* w1pT    = (float*)(ws + 4352u * 1024);
    float* l2T     = (float*)(ws + 4608u * 1024);
    float* w2pT    = (float*)(ws + 4736u * 1024);
    float* fwT     = (float*)(ws + 4864u * 1024);
    short* w2c     = (short*)(ws + 4992u * 1024);
    short* w1b     = (short*)(ws + 5136u * 1024);

    prep_kernel<<<dim3(288), 256, 0, stream>>>(s1lw, s1rw, s2lw, s2rw, c2w, c1w, c1b,
                                               fcw, l1T, w1pT, l2T, w2pT, fwT, w2c, w1b);
    fused_conv_kernel<<<dim3(4, 1024), 256, 0, stream>>>(x, w1b, w2c, c2b, pooled4);
    fc_kernel<<<dim3(1024), 256, 0, stream>>>(pooled4, fwT, fcb, mask, z1);
    sage1_kernel<<<dim3(512), 256, 0, stream>>>(z1, l1T, s1lb, w1pT, z2);
    sage2_kernel<<<dim3(512), 256, 0, stream>>>(z2, l2T, s2lb, w2pT, out);
}